// Round 5
// baseline (256.138 us; speedup 1.0000x reference)
//
#include <hip/hip_runtime.h>
#include <math.h>

#define NROWS 8192
#define KDIM  768
#define BM 128
#define BN 128
#define BK 64
#define KTILES (KDIM / BK)   // 12
#define NBC 4                // bc tiles swept per block
#define NBCG (NROWS / BN / NBC)  // 16 column groups -> grid 64*16 = 1024 = 4/CU

typedef short bf16x8 __attribute__((ext_vector_type(8)));  // 8 bf16 = 4 VGPRs
typedef float f32x4  __attribute__((ext_vector_type(4)));

static __device__ __forceinline__ unsigned short f2bf_rne(float f) {
    unsigned x = __float_as_uint(f);
    unsigned r = x + 0x7fffu + ((x >> 16) & 1u);   // round-to-nearest-even
    return (unsigned short)(r >> 16);
}
// monotonic float<->uint encoding so atomicMax(uint) == float max
static __device__ __forceinline__ unsigned enc_f(float f) {
    unsigned x = __float_as_uint(f);
    return (x & 0x80000000u) ? ~x : (x | 0x80000000u);
}
static __device__ __forceinline__ float dec_f(unsigned u) {
    unsigned x = (u & 0x80000000u) ? (u ^ 0x80000000u) : ~u;
    return __uint_as_float(x);
}

// one wave per row: float4 loads, 64-wide shfl reduce, packed ushort4 stores.
// blocks 0..31 additionally initialize the 8192-entry output to enc(-inf).
__global__ __launch_bounds__(256) void normalize_cvt_k(
        const float* __restrict__ ex, const float* __restrict__ ey,
        unsigned short* __restrict__ dst, unsigned* __restrict__ out) {
    if (blockIdx.x < NROWS / 256)
        out[blockIdx.x * 256 + threadIdx.x] = enc_f(-INFINITY);
    const int wave = threadIdx.x >> 6, lane = threadIdx.x & 63;
    const int grow = blockIdx.x * 4 + wave;          // 0..16383
    const float* src = (grow < NROWS) ? ex : ey;
    const int row = grow & (NROWS - 1);
    const float4* xr = (const float4*)(src + (size_t)row * KDIM);  // 192 float4
    float4 v[3];
    #pragma unroll
    for (int g = 0; g < 3; ++g) v[g] = xr[lane + g * 64];
    float ss = 0.f;
    #pragma unroll
    for (int g = 0; g < 3; ++g)
        ss += v[g].x * v[g].x + v[g].y * v[g].y + v[g].z * v[g].z + v[g].w * v[g].w;
    #pragma unroll
    for (int off = 32; off > 0; off >>= 1) ss += __shfl_xor(ss, off);
    const float scale = 1.0f / fmaxf(sqrtf(ss), 1e-8f);
    ushort4* dr = (ushort4*)(dst + (size_t)grow * KDIM);   // 192 ushort4
    #pragma unroll
    for (int g = 0; g < 3; ++g) {
        ushort4 o;
        o.x = f2bf_rne(v[g].x * scale); o.y = f2bf_rne(v[g].y * scale);
        o.z = f2bf_rne(v[g].z * scale); o.w = f2bf_rne(v[g].w * scale);
        dr[lane + g * 64] = o;
    }
}

// A = exn bf16 [8192][768] (rows = output rows m)
// B = eyn bf16 [8192][768] (rows = output cols n; sims = A . B^T)
// Persistent column strip: block (br,bcg) sweeps NBC bc-tiles with its A-band.
// Per-tile epilogue (shfl+atomic, R1-proven) -> no vmax registers, no spill.
// Live regs ~114 < 128 cap => __launch_bounds__(256,4) = 4 blk/CU, 16 waves/CU.
__global__ __launch_bounds__(256, 4) void gemm_rowmax_k(
        const unsigned short* __restrict__ A,
        const unsigned short* __restrict__ B,
        unsigned* __restrict__ out) {
    __shared__ unsigned short As[BM * BK];   // 16 KB
    __shared__ unsigned short Bs[BN * BK];   // 16 KB

    const int tid  = threadIdx.x;
    const int wave = tid >> 6, lane = tid & 63;
    const int br  = blockIdx.x >> 4;         // 0..63
    const int bcg = blockIdx.x & 15;         // 0..15

    // ---- staging: per issue one wave covers 8 rows x 128B, lane L -> ldsbase + L*16
    // slot s of row r holds global 16B-chunk g = s ^ (r&7)  (xor swizzle, 0 conflicts)
    const int srow   = lane >> 3;
    const int gchunk = (lane & 7) ^ srow;
    const int scol   = gchunk * 8;           // shorts
    // issue i covers rows (wave + 4i)*8 + srow  -> element offset i*24576 from base
    const unsigned short* aStage = A + (size_t)(br * BM + wave * 8 + srow) * KDIM + scol;
    unsigned short* lA = As + wave * 512;    // + i*2048
    unsigned short* lB = Bs + wave * 512;

    // ---- compute geometry: wave 64x64, 4x4 tiles of 16x16x32
    const int wm = (wave >> 1) * 64, wn = (wave & 1) * 64;
    const int quad = lane >> 4, mrow = lane & 15;
    const int c0 = quad ^ (mrow & 7);        // swizzled chunk slot, ks=1: ^4
    const unsigned short* aBase = As + (wm + mrow) * BK;
    const unsigned short* bBase = Bs + (wn + mrow) * BK;
    const int row0 = br * BM + wm + quad * 4;

    for (int bi = 0; bi < NBC; ++bi) {
        const int bc = bcg * NBC + bi;
        const unsigned short* bStage =
            B + (size_t)(bc * BN + wave * 8 + srow) * KDIM + scol;

        f32x4 acc[4][4] = {};

        for (int kt = 0; kt < KTILES; ++kt) {
            __syncthreads();   // previous tile's LDS reads done before overwrite
            #pragma unroll
            for (int i = 0; i < 4; ++i) {
                __builtin_amdgcn_global_load_lds(
                    (const __attribute__((address_space(1))) void*)(aStage + kt * BK + i * 24576),
                    (__attribute__((address_space(3))) void*)(lA + i * 2048), 16, 0, 0);
                __builtin_amdgcn_global_load_lds(
                    (const __attribute__((address_space(1))) void*)(bStage + kt * BK + i * 24576),
                    (__attribute__((address_space(3))) void*)(lB + i * 2048), 16, 0, 0);
            }
            __syncthreads();   // staging complete

            #pragma unroll
            for (int ks = 0; ks < 2; ++ks) {
                const int ck = c0 ^ (ks ? 4 : 0);
                bf16x8 af[4], bfr[4];
                #pragma unroll
                for (int mi = 0; mi < 4; ++mi)
                    af[mi] = *(const bf16x8*)(aBase + mi * 16 * BK + ck * 8);
                #pragma unroll
                for (int ni = 0; ni < 4; ++ni)
                    bfr[ni] = *(const bf16x8*)(bBase + ni * 16 * BK + ck * 8);
                #pragma unroll
                for (int mi = 0; mi < 4; ++mi)
                    #pragma unroll
                    for (int ni = 0; ni < 4; ++ni)
                        acc[mi][ni] = __builtin_amdgcn_mfma_f32_16x16x32_bf16(
                            af[mi], bfr[ni], acc[mi][ni], 0, 0, 0);
            }
        }

        // per-tile epilogue: in-lane ni fold, mrow shfl reduce, atomic merge.
        // C/D layout: col = lane&15, row = quad*4 + reg  (m89-verified)
        #pragma unroll
        for (int mi = 0; mi < 4; ++mi) {
            #pragma unroll
            for (int r = 0; r < 4; ++r) {
                float v = fmaxf(fmaxf(acc[mi][0][r], acc[mi][1][r]),
                                fmaxf(acc[mi][2][r], acc[mi][3][r]));
                v = fmaxf(v, __shfl_xor(v, 1));
                v = fmaxf(v, __shfl_xor(v, 2));
                v = fmaxf(v, __shfl_xor(v, 4));
                v = fmaxf(v, __shfl_xor(v, 8));
                if (mrow == 0)
                    atomicMax(&out[row0 + mi * 16 + r], enc_f(v));
            }
        }
    }
}

__global__ void decode_out_k(unsigned* __restrict__ u) {
    int i = blockIdx.x * 256 + threadIdx.x;
    ((float*)u)[i] = dec_f(u[i]);
}

extern "C" void kernel_launch(void* const* d_in, const int* in_sizes, int n_in,
                              void* d_out, int out_size, void* d_ws, size_t ws_size,
                              hipStream_t stream) {
    (void)in_sizes; (void)n_in; (void)out_size; (void)ws_size;
    const float* ex = (const float*)d_in[0];
    const float* ey = (const float*)d_in[1];
    unsigned short* wsb = (unsigned short*)d_ws;     // exn ++ eyn bf16 (25.2 MB)
    unsigned* outu = (unsigned*)d_out;

    normalize_cvt_k<<<(2 * NROWS) / 4, 256, 0, stream>>>(ex, ey, wsb, outu);
    gemm_rowmax_k<<<(NROWS / BM) * NBCG, 256, 0, stream>>>(
        wsb, wsb + (size_t)NROWS * KDIM, outu);
    decode_out_k<<<NROWS / 256, 256, 0, stream>>>(outu);
}

// Round 6
// 201.086 us; speedup vs baseline: 1.2738x; 1.2738x over previous
//
#include <hip/hip_runtime.h>
#include <math.h>

#define NROWS 8192
#define KDIM  768
#define BM 128
#define BN 128
#define BK 64
#define KTILES (KDIM / BK)   // 12
#define NBC 4                // bc tiles swept per block
#define NBCG (NROWS / BN / NBC)  // 16 column groups -> grid 64*16 = 1024

typedef short bf16x8 __attribute__((ext_vector_type(8)));  // 8 bf16 = 4 VGPRs
typedef float f32x4  __attribute__((ext_vector_type(4)));

static __device__ __forceinline__ unsigned short f2bf_rne(float f) {
    unsigned x = __float_as_uint(f);
    unsigned r = x + 0x7fffu + ((x >> 16) & 1u);   // round-to-nearest-even
    return (unsigned short)(r >> 16);
}
// monotonic float<->uint encoding so atomicMax(uint) == float max
static __device__ __forceinline__ unsigned enc_f(float f) {
    unsigned x = __float_as_uint(f);
    return (x & 0x80000000u) ? ~x : (x | 0x80000000u);
}
static __device__ __forceinline__ float dec_f(unsigned u) {
    unsigned x = (u & 0x80000000u) ? (u ^ 0x80000000u) : ~u;
    return __uint_as_float(x);
}

// one wave per row: float4 loads, 64-wide shfl reduce, packed ushort4 stores.
// blocks 0..31 additionally initialize the 8192-entry output to enc(-inf).
__global__ __launch_bounds__(256) void normalize_cvt_k(
        const float* __restrict__ ex, const float* __restrict__ ey,
        unsigned short* __restrict__ dst, unsigned* __restrict__ out) {
    if (blockIdx.x < NROWS / 256)
        out[blockIdx.x * 256 + threadIdx.x] = enc_f(-INFINITY);
    const int wave = threadIdx.x >> 6, lane = threadIdx.x & 63;
    const int grow = blockIdx.x * 4 + wave;          // 0..16383
    const float* src = (grow < NROWS) ? ex : ey;
    const int row = grow & (NROWS - 1);
    const float4* xr = (const float4*)(src + (size_t)row * KDIM);  // 192 float4
    float4 v[3];
    #pragma unroll
    for (int g = 0; g < 3; ++g) v[g] = xr[lane + g * 64];
    float ss = 0.f;
    #pragma unroll
    for (int g = 0; g < 3; ++g)
        ss += v[g].x * v[g].x + v[g].y * v[g].y + v[g].z * v[g].z + v[g].w * v[g].w;
    #pragma unroll
    for (int off = 32; off > 0; off >>= 1) ss += __shfl_xor(ss, off);
    const float scale = 1.0f / fmaxf(sqrtf(ss), 1e-8f);
    ushort4* dr = (ushort4*)(dst + (size_t)grow * KDIM);   // 192 ushort4
    #pragma unroll
    for (int g = 0; g < 3; ++g) {
        ushort4 o;
        o.x = f2bf_rne(v[g].x * scale); o.y = f2bf_rne(v[g].y * scale);
        o.z = f2bf_rne(v[g].z * scale); o.w = f2bf_rne(v[g].w * scale);
        dr[lane + g * 64] = o;
    }
}

// A = exn bf16 [8192][768] (rows = output rows m)
// B = eyn bf16 [8192][768] (rows = output cols n; sims = A . B^T)
// Persistent column strip: block (br,bcg) sweeps NBC bc-tiles with its A-band.
// unroll-1 on kt/ks/bi pins live regs ~112 < 128 cap of (256,4): no scratch spill.
__global__ __launch_bounds__(256, 4) void gemm_rowmax_k(
        const unsigned short* __restrict__ A,
        const unsigned short* __restrict__ B,
        unsigned* __restrict__ out) {
    __shared__ unsigned short As[BM * BK];   // 16 KB
    __shared__ unsigned short Bs[BN * BK];   // 16 KB

    const int tid  = threadIdx.x;
    const int wave = tid >> 6, lane = tid & 63;
    const int br  = blockIdx.x >> 4;         // 0..63
    const int bcg = blockIdx.x & 15;         // 0..15

    // ---- staging: per issue one wave covers 8 rows x 128B, lane L -> ldsbase + L*16
    // slot s of row r holds global 16B-chunk g = s ^ (r&7)  (xor swizzle, 0 conflicts)
    const int srow   = lane >> 3;
    const int gchunk = (lane & 7) ^ srow;
    const int scol   = gchunk * 8;           // shorts
    // issue i covers rows (wave + 4i)*8 + srow  -> element offset i*24576 from base
    const unsigned short* aStage = A + (size_t)(br * BM + wave * 8 + srow) * KDIM + scol;
    unsigned short* lA = As + wave * 512;    // + i*2048
    unsigned short* lB = Bs + wave * 512;

    // ---- compute geometry: wave 64x64, 4x4 tiles of 16x16x32
    const int wm = (wave >> 1) * 64, wn = (wave & 1) * 64;
    const int quad = lane >> 4, mrow = lane & 15;
    const int c0 = quad ^ (mrow & 7);        // swizzled chunk slot, ks=1: ^4
    const unsigned short* aBase = As + (wm + mrow) * BK;
    const unsigned short* bBase = Bs + (wn + mrow) * BK;
    const int row0 = br * BM + wm + quad * 4;

    #pragma unroll 1
    for (int bi = 0; bi < NBC; ++bi) {
        const int bc = bcg * NBC + bi;
        const unsigned short* bStage =
            B + (size_t)(bc * BN + wave * 8 + srow) * KDIM + scol;

        f32x4 acc[4][4] = {};

        #pragma unroll 1
        for (int kt = 0; kt < KTILES; ++kt) {
            __syncthreads();   // previous tile's LDS reads done before overwrite
            #pragma unroll
            for (int i = 0; i < 4; ++i) {
                __builtin_amdgcn_global_load_lds(
                    (const __attribute__((address_space(1))) void*)(aStage + kt * BK + i * 24576),
                    (__attribute__((address_space(3))) void*)(lA + i * 2048), 16, 0, 0);
                __builtin_amdgcn_global_load_lds(
                    (const __attribute__((address_space(1))) void*)(bStage + kt * BK + i * 24576),
                    (__attribute__((address_space(3))) void*)(lB + i * 2048), 16, 0, 0);
            }
            __syncthreads();   // staging complete

            #pragma unroll 1
            for (int ks = 0; ks < 2; ++ks) {
                const int ck = c0 ^ (ks << 2);
                bf16x8 af[4], bfr[4];
                #pragma unroll
                for (int mi = 0; mi < 4; ++mi)
                    af[mi] = *(const bf16x8*)(aBase + mi * 16 * BK + ck * 8);
                #pragma unroll
                for (int ni = 0; ni < 4; ++ni)
                    bfr[ni] = *(const bf16x8*)(bBase + ni * 16 * BK + ck * 8);
                #pragma unroll
                for (int mi = 0; mi < 4; ++mi)
                    #pragma unroll
                    for (int ni = 0; ni < 4; ++ni)
                        acc[mi][ni] = __builtin_amdgcn_mfma_f32_16x16x32_bf16(
                            af[mi], bfr[ni], acc[mi][ni], 0, 0, 0);
            }
        }

        // per-tile epilogue: in-lane ni fold, mrow shfl reduce, atomic merge.
        // C/D layout: col = lane&15, row = quad*4 + reg  (m89-verified)
        #pragma unroll
        for (int mi = 0; mi < 4; ++mi) {
            #pragma unroll
            for (int r = 0; r < 4; ++r) {
                float v = fmaxf(fmaxf(acc[mi][0][r], acc[mi][1][r]),
                                fmaxf(acc[mi][2][r], acc[mi][3][r]));
                v = fmaxf(v, __shfl_xor(v, 1));
                v = fmaxf(v, __shfl_xor(v, 2));
                v = fmaxf(v, __shfl_xor(v, 4));
                v = fmaxf(v, __shfl_xor(v, 8));
                if (mrow == 0)
                    atomicMax(&out[row0 + mi * 16 + r], enc_f(v));
            }
        }
    }
}

__global__ void decode_out_k(unsigned* __restrict__ u) {
    int i = blockIdx.x * 256 + threadIdx.x;
    ((float*)u)[i] = dec_f(u[i]);
}

extern "C" void kernel_launch(void* const* d_in, const int* in_sizes, int n_in,
                              void* d_out, int out_size, void* d_ws, size_t ws_size,
                              hipStream_t stream) {
    (void)in_sizes; (void)n_in; (void)out_size; (void)ws_size;
    const float* ex = (const float*)d_in[0];
    const float* ey = (const float*)d_in[1];
    unsigned short* wsb = (unsigned short*)d_ws;     // exn ++ eyn bf16 (25.2 MB)
    unsigned* outu = (unsigned*)d_out;

    normalize_cvt_k<<<(2 * NROWS) / 4, 256, 0, stream>>>(ex, ey, wsb, outu);
    gemm_rowmax_k<<<(NROWS / BM) * NBCG, 256, 0, stream>>>(
        wsb, wsb + (size_t)NROWS * KDIM, outu);
    decode_out_k<<<NROWS / 256, 256, 0, stream>>>(outu);
}